// Round 1
// baseline (408.007 us; speedup 1.0000x reference)
//
#include <hip/hip_runtime.h>
#include <math.h>

#define EULER_F 0.5772156649015329f
#define FLT_MAX_F 3.4028234663852886e38f

// Ei(t) for t < 0, exactly mirroring the reference's series construction:
//   E1 power series (30 terms) for x < 8, asymptotic (8 terms) for x >= 8,
//   both branches computed, then selected (matches jnp.where numerics).
__device__ __forceinline__ float expi_neg(float t) {
    float x = -t;
    float xs = fminf(x, 8.0f);
    float s = 0.0f;
    float term = xs;
#pragma unroll
    for (int k = 1; k <= 30; ++k) {
        s = s + term * (1.0f / (float)k);            // constant-folded reciprocals
        term = term * (-xs) * (1.0f / (float)(k + 1));
    }
    float e1_small = -EULER_F - __logf(xs) + s;

    float xl = fmaxf(x, 8.0f);
    float rxl = 1.0f / xl;
    float a = 1.0f, acc = 1.0f;
#pragma unroll
    for (int n = 1; n <= 8; ++n) {
        a = a * (-(float)n) * rxl;
        acc = acc + a;
    }
    float e1_large = __expf(-xl) * rxl * acc;

    float e1 = (x < 8.0f) ? e1_small : e1_large;
    return -e1;
}

// One dense layer over a 64-row LDS tile.
// Thread t computes a 2-col x R-row register tile.
//   col group g = t % (N/2)  -> cols [2g, 2g+1]   (lane-consecutive => coalesced W loads)
//   row group rg = t / (N/2) -> rows [rg*R, rg*R+R)
// Activation reads are wave-uniform ds_read_b128 (broadcast, conflict-free).
template <int K, int N, bool RELU>
__device__ __forceinline__ void layer(const float* __restrict__ in_lds,
                                      float* __restrict__ out_lds,
                                      const float* __restrict__ W,
                                      const float* __restrict__ bias,
                                      int t) {
    constexpr int G = N / 2;          // column groups
    constexpr int R = G / 4;          // rows per thread (64*N/2 outputs / 256 threads / ... )
    static_assert(256 % G == 0, "col groups must divide block");
    static_assert(64 % R == 0 && (256 / G) * R == 64, "row coverage");

    const int g = t % G;
    const int rg = t / G;
    const int r0 = rg * R;

    float2 acc[R];
    const float2 bv = *(const float2*)(bias + 2 * g);
#pragma unroll
    for (int r = 0; r < R; ++r) acc[r] = bv;

    const float* Wg = W + 2 * g;
    const float* in0 = in_lds + r0 * K;

    for (int k = 0; k < K; k += 4) {
        float2 w0 = *(const float2*)(Wg + (size_t)(k + 0) * N);
        float2 w1 = *(const float2*)(Wg + (size_t)(k + 1) * N);
        float2 w2 = *(const float2*)(Wg + (size_t)(k + 2) * N);
        float2 w3 = *(const float2*)(Wg + (size_t)(k + 3) * N);
#pragma unroll
        for (int r = 0; r < R; ++r) {
            float4 av = *(const float4*)(in0 + r * K + k);
            acc[r].x = fmaf(av.x, w0.x, acc[r].x);
            acc[r].y = fmaf(av.x, w0.y, acc[r].y);
            acc[r].x = fmaf(av.y, w1.x, acc[r].x);
            acc[r].y = fmaf(av.y, w1.y, acc[r].y);
            acc[r].x = fmaf(av.z, w2.x, acc[r].x);
            acc[r].y = fmaf(av.z, w2.y, acc[r].y);
            acc[r].x = fmaf(av.w, w3.x, acc[r].x);
            acc[r].y = fmaf(av.w, w3.y, acc[r].y);
        }
    }

#pragma unroll
    for (int r = 0; r < R; ++r) {
        float2 v = acc[r];
        if (RELU) {
            v.x = fmaxf(v.x, 0.0f);
            v.y = fmaxf(v.y, 0.0f);
        }
        *(float2*)(out_lds + (size_t)(r0 + r) * N + 2 * g) = v;
    }
}

__global__ __launch_bounds__(256, 2) void mlp_phi_kernel(
    const float* __restrict__ u,
    const float* __restrict__ W0, const float* __restrict__ b0,
    const float* __restrict__ W1, const float* __restrict__ b1,
    const float* __restrict__ W2, const float* __restrict__ b2,
    const float* __restrict__ W3, const float* __restrict__ b3,
    const float* __restrict__ var1, const float* __restrict__ var2,
    const float* __restrict__ var3, const float* __restrict__ var4,
    const float* __restrict__ var5, const float* __restrict__ var6,
    float* __restrict__ out) {
    // Ping-pong activation buffers: 2 x 64x128 fp32 = 64 KiB LDS total.
    __shared__ float smem[2 * 64 * 128];
    float* bufA = smem;
    float* bufB = smem + 64 * 128;

    const int t = threadIdx.x;
    const size_t rowBase = (size_t)blockIdx.x * 64;
    const float* uT = u + rowBase * 64;

    // Stage u tile (64 rows x 64 cols) into bufA, coalesced float4.
#pragma unroll
    for (int i = 0; i < 4; ++i) {
        const int idx = t + 256 * i;  // float4 index, 1024 total
        *(float4*)(bufA + (size_t)idx * 4) = *(const float4*)(uT + (size_t)idx * 4);
    }
    __syncthreads();

    layer<64, 128, true>(bufA, bufB, W0, b0, t);
    __syncthreads();
    layer<128, 128, true>(bufB, bufA, W1, b1, t);
    __syncthreads();
    layer<128, 64, true>(bufA, bufB, W2, b2, t);
    __syncthreads();
    layer<64, 32, false>(bufB, bufA, W3, b3, t);   // net, no relu
    __syncthreads();

    // Epilogue: 64x32 = 2048 outputs, 8 per thread, coalesced.
    float* outT = out + rowBase * 32;
#pragma unroll
    for (int i = 0; i < 8; ++i) {
        const int idx = t + 256 * i;       // 0..2047
        const int row = idx >> 5;
        const int d = idx & 31;

        const float net = bufA[idx];       // pitch 32 => linear
        const float ud = uT[(size_t)row * 64 + d];

        const float lt = __logf(1.0f - ud);      // log_term < 0
        const float li = expi_neg(lt);           // _li(1-u) = Ei(log(1-u))
        const float omu = 1.0f - ud;

        const float phi = var2[d] / lt
                        + var3[d] * li
                        + var4[d] * (omu / lt - li)
                        + var5[d] * (omu * (lt + 1.0f) / (2.0f * lt * lt) - 0.5f * li);

        const float ud2 = ud * ud;
        const float ud4 = ud2 * ud2;
        const float p01 = -4.0f * ud4 * ud + 5.0f * ud4;   // -4u^5 + 5u^4

        float corr1 = p01 * (var1[d] + phi);
        if (isnan(corr1)) {
            corr1 = 0.0f;                                   // nan_to_num(nan=0)
        } else if (isinf(corr1)) {
            corr1 = copysignf(FLT_MAX_F, corr1);            // nan_to_num inf clamp
        }
        const float corr2 = var6[d] * (ud * ud2 - 2.0f * ud2 + ud);

        float nt = net + corr1 + corr2;
        nt = fmaxf(nt, 0.0f);                               // relu

        const float base = (1.0f - ud2) * 0.5f;
        outT[idx] = __expf(-nt * __logf(base));             // base^(-nt)
    }
}

extern "C" void kernel_launch(void* const* d_in, const int* in_sizes, int n_in,
                              void* d_out, int out_size, void* d_ws, size_t ws_size,
                              hipStream_t stream) {
    const float* u    = (const float*)d_in[0];
    const float* W0   = (const float*)d_in[1];
    const float* b0   = (const float*)d_in[2];
    const float* W1   = (const float*)d_in[3];
    const float* b1   = (const float*)d_in[4];
    const float* W2   = (const float*)d_in[5];
    const float* b2   = (const float*)d_in[6];
    const float* W3   = (const float*)d_in[7];
    const float* b3   = (const float*)d_in[8];
    const float* var1 = (const float*)d_in[9];
    const float* var2 = (const float*)d_in[10];
    const float* var3 = (const float*)d_in[11];
    const float* var4 = (const float*)d_in[12];
    const float* var5 = (const float*)d_in[13];
    const float* var6 = (const float*)d_in[14];
    float* out = (float*)d_out;

    const int B = in_sizes[0] / 64;        // 262144 rows
    const int blocks = B / 64;             // 64 rows per block
    mlp_phi_kernel<<<dim3(blocks), dim3(256), 0, stream>>>(
        u, W0, b0, W1, b1, W2, b2, W3, b3,
        var1, var2, var3, var4, var5, var6, out);
}

// Round 2
// 222.570 us; speedup vs baseline: 1.8332x; 1.8332x over previous
//
#include <hip/hip_runtime.h>
#include <hip/hip_bf16.h>
#include <math.h>

#define EULER_F 0.5772156649015329f
#define FLT_MAX_F 3.4028234663852886e38f
#define PITCH 132   // 128 + 4 floats: keeps 16B alignment, breaks power-of-2 bank stride

typedef __attribute__((ext_vector_type(8))) short short8;   // 8 bf16 = 4 VGPRs (MFMA A/B frag)
typedef __attribute__((ext_vector_type(4))) float f32x4;    // MFMA C/D frag

// ---------------- bf16 split helpers ----------------
// a = hi + lo with hi = bf16_rne(a), lo = bf16_rne(a - hi). 3-term MFMA product
// hi*hi + lo*hi + hi*lo has relative error ~2^-18 (drops only lo*lo).
__device__ __forceinline__ void split8(const float4 a0, const float4 a1,
                                       short8& hi, short8& lo) {
    float a[8] = {a0.x, a0.y, a0.z, a0.w, a1.x, a1.y, a1.z, a1.w};
#pragma unroll
    for (int p = 0; p < 4; ++p) {
        float2 f = make_float2(a[2 * p], a[2 * p + 1]);
        __hip_bfloat162 h = __float22bfloat162_rn(f);          // v_cvt_pk_bf16_f32
        float2 hf = __bfloat1622float2(h);
        __hip_bfloat162 l = __float22bfloat162_rn(make_float2(f.x - hf.x, f.y - hf.y));
        union { __hip_bfloat162 b; short2 s; } uh, ul;
        uh.b = h; ul.b = l;
        hi[2 * p] = uh.s.x; hi[2 * p + 1] = uh.s.y;
        lo[2 * p] = ul.s.x; lo[2 * p + 1] = ul.s.y;
    }
}

// ---------------- weight prep: fp32 W -> bf16 hi/lo in B-fragment order ----------------
// Fragment layout for mfma_f32_16x16x32_bf16 (m89/m120-verified):
//   A: lane l holds A[m = l&15][k = (l>>4)*8 + j], j=0..7
//   B: lane l holds B[k = (l>>4)*8 + j][n = l&15]
//   C/D: lane l holds D[row = (l>>4)*4 + r][col = l&15], r=0..3
// ws layout (shorts): per layer, chunk-pair cp = ct*NK + s occupies 1024 shorts:
//   [cp*1024 + lane*8 + j]        = hi bits
//   [cp*1024 + 512 + lane*8 + j]  = lo bits
// Layer bases (shorts): L0=0 (64x128), L1=16384 (128x128), L2=49152 (128x64), L3=65536 (64x32).
__global__ void prep_weights(const float* __restrict__ W0, const float* __restrict__ W1,
                             const float* __restrict__ W2, const float* __restrict__ W3,
                             short* __restrict__ ws) {
    int e = blockIdx.x * 256 + threadIdx.x;
    const float* W; int N, NK, base, el;
    if (e < 8192)       { W = W0; N = 128; NK = 2; base = 0;     el = e; }
    else if (e < 24576) { W = W1; N = 128; NK = 4; base = 16384; el = e - 8192; }
    else if (e < 32768) { W = W2; N = 64;  NK = 4; base = 49152; el = e - 24576; }
    else if (e < 34816) { W = W3; N = 32;  NK = 2; base = 65536; el = e - 32768; }
    else return;
    int cp = el >> 9, r = el & 511, lane = r >> 3, j = r & 7;
    int s = cp % NK, ct = cp / NK;
    int k = s * 32 + (lane >> 4) * 8 + j;
    int n = ct * 16 + (lane & 15);
    float w = W[k * N + n];
    __hip_bfloat16 h = __float2bfloat16(w);
    float hf = __bfloat162float(h);
    __hip_bfloat16 l = __float2bfloat16(w - hf);
    union { __hip_bfloat16 b; short s; } ph, pl;
    ph.b = h; pl.b = l;
    ws[base + cp * 1024 + lane * 8 + j] = ph.s;
    ws[base + cp * 1024 + 512 + lane * 8 + j] = pl.s;
}

// ---------------- per-wave layer compute ----------------
template <int K, int N>
__device__ __forceinline__ void layer_frag(const short8* __restrict__ wf,
                                           const float* __restrict__ bias,
                                           const short8 ah[K / 32], const short8 al[K / 32],
                                           int lane, int m, f32x4* acc) {
    constexpr int NK = K / 32, NT = N / 16;
#pragma unroll
    for (int ct = 0; ct < NT; ++ct) {
        float b = bias[ct * 16 + m];
        acc[ct] = f32x4{b, b, b, b};
    }
#pragma unroll
    for (int s = 0; s < NK; ++s) {
#pragma unroll
        for (int ct = 0; ct < NT; ++ct) {
            const short8* ch = wf + (size_t)(ct * NK + s) * 128;
            short8 bh = ch[lane];
            short8 bl = ch[64 + lane];
            acc[ct] = __builtin_amdgcn_mfma_f32_16x16x32_bf16(ah[s], bh, acc[ct], 0, 0, 0);
            acc[ct] = __builtin_amdgcn_mfma_f32_16x16x32_bf16(al[s], bh, acc[ct], 0, 0, 0);
            acc[ct] = __builtin_amdgcn_mfma_f32_16x16x32_bf16(ah[s], bl, acc[ct], 0, 0, 0);
        }
    }
}

template <int K>
__device__ __forceinline__ void load_a_lds(const float* __restrict__ lw, int m, int q,
                                           short8 ah[K / 32], short8 al[K / 32]) {
    const float* rp = lw + m * PITCH + q * 8;
#pragma unroll
    for (int s = 0; s < K / 32; ++s) {
        const float* p = rp + s * 32;
        split8(*(const float4*)p, *(const float4*)(p + 4), ah[s], al[s]);
    }
}

template <int N>
__device__ __forceinline__ void store_d_lds(float* __restrict__ lw, int m, int q,
                                            const f32x4* acc, bool relu) {
#pragma unroll
    for (int ct = 0; ct < N / 16; ++ct) {
#pragma unroll
        for (int r = 0; r < 4; ++r) {
            float v = acc[ct][r];
            if (relu) v = fmaxf(v, 0.0f);
            lw[(q * 4 + r) * PITCH + ct * 16 + m] = v;
        }
    }
}

// ---------------- epilogue math (identical numerics to round-0, verified) ----------------
__device__ __forceinline__ float expi_neg(float t) {
    float x = -t;
    float xs = fminf(x, 8.0f);
    float s = 0.0f;
    float term = xs;
#pragma unroll
    for (int k = 1; k <= 30; ++k) {
        s = s + term * (1.0f / (float)k);
        term = term * (-xs) * (1.0f / (float)(k + 1));
    }
    float e1_small = -EULER_F - __logf(xs) + s;
    float xl = fmaxf(x, 8.0f);
    float rxl = 1.0f / xl;
    float a = 1.0f, accv = 1.0f;
#pragma unroll
    for (int n = 1; n <= 8; ++n) {
        a = a * (-(float)n) * rxl;
        accv = accv + a;
    }
    float e1_large = __expf(-xl) * rxl * accv;
    float e1 = (x < 8.0f) ? e1_small : e1_large;
    return -e1;
}

__global__ __launch_bounds__(256, 4) void mlp_phi_mfma(
    const float* __restrict__ u,
    const float* __restrict__ b0, const float* __restrict__ b1,
    const float* __restrict__ b2, const float* __restrict__ b3,
    const short* __restrict__ ws,
    const float* __restrict__ var1, const float* __restrict__ var2,
    const float* __restrict__ var3, const float* __restrict__ var4,
    const float* __restrict__ var5, const float* __restrict__ var6,
    float* __restrict__ out) {
    // 4 waves/block, each wave owns 16 rows end-to-end. No __syncthreads anywhere.
    __shared__ float lds[4 * 16 * PITCH];   // 33792 B -> 4 blocks/CU
    const int t = threadIdx.x, lane = t & 63, wave = t >> 6;
    const int m = lane & 15, q = lane >> 4;
    float* lw = lds + wave * 16 * PITCH;
    const size_t row0 = (size_t)blockIdx.x * 64 + wave * 16;

    const short8* wf0 = (const short8*)(ws);
    const short8* wf1 = (const short8*)(ws + 16384);
    const short8* wf2 = (const short8*)(ws + 49152);
    const short8* wf3 = (const short8*)(ws + 65536);

    short8 ah[4], al[4];
    f32x4 acc[8];

    // ---- Layer 0 (64 -> 128): A straight from global u ----
    {
        const float* up = u + (row0 + m) * 64;
#pragma unroll
        for (int s = 0; s < 2; ++s) {
            const float* p = up + s * 32 + q * 8;
            split8(*(const float4*)p, *(const float4*)(p + 4), ah[s], al[s]);
        }
    }
    layer_frag<64, 128>(wf0, b0, ah, al, lane, m, acc);
    store_d_lds<128>(lw, m, q, acc, true);

    // ---- Layer 1 (128 -> 128) ----
    load_a_lds<128>(lw, m, q, ah, al);
    layer_frag<128, 128>(wf1, b1, ah, al, lane, m, acc);
    store_d_lds<128>(lw, m, q, acc, true);

    // ---- Layer 2 (128 -> 64) ----
    load_a_lds<128>(lw, m, q, ah, al);
    layer_frag<128, 64>(wf2, b2, ah, al, lane, m, acc);
    store_d_lds<64>(lw, m, q, acc, true);

    // ---- Layer 3 (64 -> 32): net stays in registers ----
    load_a_lds<64>(lw, m, q, ah, al);
    layer_frag<64, 32>(wf3, b3, ah, al, lane, m, acc);   // acc[0..1] = net tiles

    // ---- Epilogue: lane holds net[row=q*4+r][col=ot*16+m] ----
#pragma unroll
    for (int ot = 0; ot < 2; ++ot) {
        const int d = ot * 16 + m;
        const float v1 = var1[d], v2 = var2[d], v3 = var3[d],
                    v4 = var4[d], v5 = var5[d], v6 = var6[d];
#pragma unroll
        for (int r = 0; r < 4; ++r) {
            const size_t row = row0 + q * 4 + r;
            const float net = acc[ot][r];
            const float ud = u[row * 64 + d];

            const float lt = __logf(1.0f - ud);
            const float li = expi_neg(lt);
            const float omu = 1.0f - ud;

            const float phi = v2 / lt
                            + v3 * li
                            + v4 * (omu / lt - li)
                            + v5 * (omu * (lt + 1.0f) / (2.0f * lt * lt) - 0.5f * li);

            const float ud2 = ud * ud;
            const float ud4 = ud2 * ud2;
            const float p01 = -4.0f * ud4 * ud + 5.0f * ud4;

            float corr1 = p01 * (v1 + phi);
            if (isnan(corr1)) {
                corr1 = 0.0f;
            } else if (isinf(corr1)) {
                corr1 = copysignf(FLT_MAX_F, corr1);
            }
            const float corr2 = v6 * (ud * ud2 - 2.0f * ud2 + ud);

            float nt = net + corr1 + corr2;
            nt = fmaxf(nt, 0.0f);

            const float base = (1.0f - ud2) * 0.5f;
            out[row * 32 + d] = __expf(-nt * __logf(base));
        }
    }
}

extern "C" void kernel_launch(void* const* d_in, const int* in_sizes, int n_in,
                              void* d_out, int out_size, void* d_ws, size_t ws_size,
                              hipStream_t stream) {
    const float* u    = (const float*)d_in[0];
    const float* W0   = (const float*)d_in[1];
    const float* b0   = (const float*)d_in[2];
    const float* W1   = (const float*)d_in[3];
    const float* b1   = (const float*)d_in[4];
    const float* W2   = (const float*)d_in[5];
    const float* b2   = (const float*)d_in[6];
    const float* W3   = (const float*)d_in[7];
    const float* b3   = (const float*)d_in[8];
    const float* var1 = (const float*)d_in[9];
    const float* var2 = (const float*)d_in[10];
    const float* var3 = (const float*)d_in[11];
    const float* var4 = (const float*)d_in[12];
    const float* var5 = (const float*)d_in[13];
    const float* var6 = (const float*)d_in[14];
    float* out = (float*)d_out;
    short* ws = (short*)d_ws;   // needs 139,264 B

    // Convert weights to bf16 hi/lo fragment layout (same work every launch).
    prep_weights<<<dim3(136), dim3(256), 0, stream>>>(W0, W1, W2, W3, ws);

    const int B = in_sizes[0] / 64;        // 262144 rows
    const int blocks = B / 64;             // 64 rows per block (16 per wave)
    mlp_phi_mfma<<<dim3(blocks), dim3(256), 0, stream>>>(
        u, b0, b1, b2, b3, ws,
        var1, var2, var3, var4, var5, var6, out);
}

// Round 3
// 203.577 us; speedup vs baseline: 2.0042x; 1.0933x over previous
//
#include <hip/hip_runtime.h>
#include <hip/hip_bf16.h>
#include <math.h>

#define FLT_MAX_F 3.4028234663852886e38f
#define PITCH 132   // 128 + 4 floats: keeps 16B alignment, breaks power-of-2 bank stride

typedef __attribute__((ext_vector_type(8))) short short8;   // 8 bf16 = 4 VGPRs (MFMA A/B frag)
typedef __attribute__((ext_vector_type(4))) float f32x4;    // MFMA C/D frag

// ---------------- bf16 split helpers ----------------
// a = hi + lo with hi = bf16_rne(a), lo = bf16_rne(a - hi). 3-term MFMA product
// hi*hi + lo*hi + hi*lo has relative error ~2^-18 (drops only lo*lo).
__device__ __forceinline__ void split8(const float4 a0, const float4 a1,
                                       short8& hi, short8& lo) {
    float a[8] = {a0.x, a0.y, a0.z, a0.w, a1.x, a1.y, a1.z, a1.w};
#pragma unroll
    for (int p = 0; p < 4; ++p) {
        float2 f = make_float2(a[2 * p], a[2 * p + 1]);
        __hip_bfloat162 h = __float22bfloat162_rn(f);          // v_cvt_pk_bf16_f32
        float2 hf = __bfloat1622float2(h);
        __hip_bfloat162 l = __float22bfloat162_rn(make_float2(f.x - hf.x, f.y - hf.y));
        union { __hip_bfloat162 b; short2 s; } uh, ul;
        uh.b = h; ul.b = l;
        hi[2 * p] = uh.s.x; hi[2 * p + 1] = uh.s.y;
        lo[2 * p] = ul.s.x; lo[2 * p + 1] = ul.s.y;
    }
}

// ---------------- weight prep: fp32 W -> bf16 hi/lo in B-fragment order ----------------
// Inverted mapping vs round 2: thread id = row-major (k,n) element -> COALESCED W reads;
// scattered LDS-order writes are latency-tolerant (fire-and-forget).
// Fragment layout for mfma_f32_16x16x32_bf16:
//   B: lane l holds B[k = s*32 + (l>>4)*8 + j][n = ct*16 + (l&15)]
// ws layout (shorts): per layer, chunk-pair cp = ct*NK + s occupies 1024 shorts:
//   [cp*1024 + lane*8 + j] = hi, [cp*1024 + 512 + lane*8 + j] = lo.
// Layer bases (shorts): L0=0 (64x128), L1=16384 (128x128), L2=49152 (128x64), L3=65536 (64x32).
__global__ void prep_weights(const float* __restrict__ W0, const float* __restrict__ W1,
                             const float* __restrict__ W2, const float* __restrict__ W3,
                             short* __restrict__ ws) {
    int e = blockIdx.x * 256 + threadIdx.x;
    const float* W; int logN, NK, base, el;
    if (e < 8192)       { W = W0; logN = 7; NK = 2; base = 0;     el = e; }
    else if (e < 24576) { W = W1; logN = 7; NK = 4; base = 16384; el = e - 8192; }
    else if (e < 32768) { W = W2; logN = 6; NK = 4; base = 49152; el = e - 24576; }
    else if (e < 34816) { W = W3; logN = 5; NK = 2; base = 65536; el = e - 32768; }
    else return;
    int k = el >> logN;
    int n = el & ((1 << logN) - 1);
    int s = k >> 5, kl = k & 31;
    int lane = (kl >> 3) * 16 + (n & 15);
    int j = kl & 7;
    int ct = n >> 4;
    int cp = ct * NK + s;
    float w = W[el];                       // coalesced: consecutive threads, consecutive addrs
    __hip_bfloat16 h = __float2bfloat16(w);
    float hf = __bfloat162float(h);
    __hip_bfloat16 l = __float2bfloat16(w - hf);
    union { __hip_bfloat16 b; short s; } ph, pl;
    ph.b = h; pl.b = l;
    ws[base + cp * 1024 + lane * 8 + j] = ph.s;
    ws[base + cp * 1024 + 512 + lane * 8 + j] = pl.s;
}

// ---------------- per-wave layer compute ----------------
template <int K, int N>
__device__ __forceinline__ void layer_frag(const short8* __restrict__ wf,
                                           const float* __restrict__ bias,
                                           const short8 ah[K / 32], const short8 al[K / 32],
                                           int lane, int m, f32x4* acc) {
    constexpr int NK = K / 32, NT = N / 16;
#pragma unroll
    for (int ct = 0; ct < NT; ++ct) {
        float b = bias[ct * 16 + m];
        acc[ct] = f32x4{b, b, b, b};
    }
#pragma unroll
    for (int s = 0; s < NK; ++s) {
#pragma unroll
        for (int ct = 0; ct < NT; ++ct) {
            const short8* ch = wf + (size_t)(ct * NK + s) * 128;
            short8 bh = ch[lane];
            short8 bl = ch[64 + lane];
            acc[ct] = __builtin_amdgcn_mfma_f32_16x16x32_bf16(ah[s], bh, acc[ct], 0, 0, 0);
            acc[ct] = __builtin_amdgcn_mfma_f32_16x16x32_bf16(al[s], bh, acc[ct], 0, 0, 0);
            acc[ct] = __builtin_amdgcn_mfma_f32_16x16x32_bf16(ah[s], bl, acc[ct], 0, 0, 0);
        }
    }
}

template <int K>
__device__ __forceinline__ void load_a_lds(const float* __restrict__ lw, int m, int q,
                                           short8 ah[K / 32], short8 al[K / 32]) {
    const float* rp = lw + m * PITCH + q * 8;
#pragma unroll
    for (int s = 0; s < K / 32; ++s) {
        const float* p = rp + s * 32;
        split8(*(const float4*)p, *(const float4*)(p + 4), ah[s], al[s]);
    }
}

template <int N>
__device__ __forceinline__ void store_d_lds(float* __restrict__ lw, int m, int q,
                                            const f32x4* acc, bool relu) {
#pragma unroll
    for (int ct = 0; ct < N / 16; ++ct) {
#pragma unroll
        for (int r = 0; r < 4; ++r) {
            float v = acc[ct][r];
            if (relu) v = fmaxf(v, 0.0f);
            lw[(q * 4 + r) * PITCH + ct * 16 + m] = v;
        }
    }
}

// ---------------- fast E1: Abramowitz-Stegun rational approximations ----------------
// li(1-u) = Ei(t) = -E1(-t), t = log(1-u) < 0; x = -t in (1e-4, 9.3).
// x < 1:  5.1.53 power polynomial + log, |err| < 2e-7
// x >= 1: 5.1.54 rational (deg 4/4), x e^x E1 = P/Q, |err| < 2e-8
// Both错误 are ~4 orders below the delta-nt tolerance budget (~2e-3); the
// reference's own fp32 30-term series carries ~1e-5 cancellation noise near x=8.
__device__ __forceinline__ float expi_neg_fast(float t) {
    float x = -t;
    float e1s = -__logf(x) + (-0.57721566f + x * (0.99999193f + x * (-0.24991055f
              + x * (0.05519968f + x * (-0.00976004f + x * 0.00107857f)))));
    float num = 0.2677737343f + x * (8.6347608925f + x * (18.0590169730f
              + x * (8.5733287401f + x)));
    float den = 3.9584969228f + x * (21.0996530827f + x * (25.6329561486f
              + x * (9.5733223454f + x)));
    float e1l = __expf(-x) * num * __builtin_amdgcn_rcpf(x * den);
    float e1 = (x < 1.0f) ? e1s : e1l;
    return -e1;
}

__global__ __launch_bounds__(256, 4) void mlp_phi_mfma(
    const float* __restrict__ u,
    const float* __restrict__ b0, const float* __restrict__ b1,
    const float* __restrict__ b2, const float* __restrict__ b3,
    const short* __restrict__ ws,
    const float* __restrict__ var1, const float* __restrict__ var2,
    const float* __restrict__ var3, const float* __restrict__ var4,
    const float* __restrict__ var5, const float* __restrict__ var6,
    float* __restrict__ out) {
    // 4 waves/block, each wave owns 16 rows end-to-end. No __syncthreads anywhere.
    __shared__ float lds[4 * 16 * PITCH];   // 33792 B -> 4 blocks/CU
    const int t = threadIdx.x, lane = t & 63, wave = t >> 6;
    const int m = lane & 15, q = lane >> 4;
    float* lw = lds + wave * 16 * PITCH;
    const size_t row0 = (size_t)blockIdx.x * 64 + wave * 16;

    const short8* wf0 = (const short8*)(ws);
    const short8* wf1 = (const short8*)(ws + 16384);
    const short8* wf2 = (const short8*)(ws + 49152);
    const short8* wf3 = (const short8*)(ws + 65536);

    short8 ah[4], al[4];
    f32x4 acc[8];

    // ---- Layer 0 (64 -> 128): A straight from global u ----
    {
        const float* up = u + (row0 + m) * 64;
#pragma unroll
        for (int s = 0; s < 2; ++s) {
            const float* p = up + s * 32 + q * 8;
            split8(*(const float4*)p, *(const float4*)(p + 4), ah[s], al[s]);
        }
    }
    layer_frag<64, 128>(wf0, b0, ah, al, lane, m, acc);
    store_d_lds<128>(lw, m, q, acc, true);

    // ---- Layer 1 (128 -> 128) ----
    load_a_lds<128>(lw, m, q, ah, al);
    layer_frag<128, 128>(wf1, b1, ah, al, lane, m, acc);
    store_d_lds<128>(lw, m, q, acc, true);

    // ---- Layer 2 (128 -> 64) ----
    load_a_lds<128>(lw, m, q, ah, al);
    layer_frag<128, 64>(wf2, b2, ah, al, lane, m, acc);
    store_d_lds<64>(lw, m, q, acc, true);

    // ---- Layer 3 (64 -> 32): net stays in registers ----
    load_a_lds<64>(lw, m, q, ah, al);
    layer_frag<64, 32>(wf3, b3, ah, al, lane, m, acc);   // acc[0..1] = net tiles

    // ---- Epilogue: lane holds net[row=q*4+r][col=ot*16+m] ----
#pragma unroll
    for (int ot = 0; ot < 2; ++ot) {
        const int d = ot * 16 + m;
        const float v1 = var1[d], v2 = var2[d], v3 = var3[d],
                    v4 = var4[d], v5 = var5[d], v6 = var6[d];
#pragma unroll
        for (int r = 0; r < 4; ++r) {
            const size_t row = row0 + q * 4 + r;
            const float net = acc[ot][r];
            const float ud = u[row * 64 + d];

            const float lt = __logf(1.0f - ud);      // log_term < 0
            const float li = expi_neg_fast(lt);
            const float omu = 1.0f - ud;

            const float rl = __builtin_amdgcn_rcpf(lt);   // 1/log_term
            const float phi = v2 * rl
                            + v3 * li
                            + v4 * (omu * rl - li)
                            + v5 * (omu * (lt + 1.0f) * 0.5f * (rl * rl) - 0.5f * li);

            const float ud2 = ud * ud;
            const float ud4 = ud2 * ud2;
            const float p01 = -4.0f * ud4 * ud + 5.0f * ud4;

            float corr1 = p01 * (v1 + phi);
            if (isnan(corr1)) {
                corr1 = 0.0f;
            } else if (isinf(corr1)) {
                corr1 = copysignf(FLT_MAX_F, corr1);
            }
            const float corr2 = v6 * (ud * ud2 - 2.0f * ud2 + ud);

            float nt = net + corr1 + corr2;
            nt = fmaxf(nt, 0.0f);

            const float base = (1.0f - ud2) * 0.5f;
            out[row * 32 + d] = __expf(-nt * __logf(base));
        }
    }
}

extern "C" void kernel_launch(void* const* d_in, const int* in_sizes, int n_in,
                              void* d_out, int out_size, void* d_ws, size_t ws_size,
                              hipStream_t stream) {
    const float* u    = (const float*)d_in[0];
    const float* W0   = (const float*)d_in[1];
    const float* b0   = (const float*)d_in[2];
    const float* W1   = (const float*)d_in[3];
    const float* b1   = (const float*)d_in[4];
    const float* W2   = (const float*)d_in[5];
    const float* b2   = (const float*)d_in[6];
    const float* W3   = (const float*)d_in[7];
    const float* b3   = (const float*)d_in[8];
    const float* var1 = (const float*)d_in[9];
    const float* var2 = (const float*)d_in[10];
    const float* var3 = (const float*)d_in[11];
    const float* var4 = (const float*)d_in[12];
    const float* var5 = (const float*)d_in[13];
    const float* var6 = (const float*)d_in[14];
    float* out = (float*)d_out;
    short* ws = (short*)d_ws;   // needs 139,264 B

    // Convert weights to bf16 hi/lo fragment layout (same work every launch).
    prep_weights<<<dim3(136), dim3(256), 0, stream>>>(W0, W1, W2, W3, ws);

    const int B = in_sizes[0] / 64;        // 262144 rows
    const int blocks = B / 64;             // 64 rows per block (16 per wave)
    mlp_phi_mfma<<<dim3(blocks), dim3(256), 0, stream>>>(
        u, b0, b1, b2, b3, ws,
        var1, var2, var3, var4, var5, var6, out);
}

// Round 4
// 200.725 us; speedup vs baseline: 2.0327x; 1.0142x over previous
//
#include <hip/hip_runtime.h>
#include <hip/hip_bf16.h>
#include <math.h>

#define FLT_MAX_F 3.4028234663852886e38f
#define PITCH 132   // 128 + 4 floats: keeps 16B alignment, breaks power-of-2 bank stride

typedef __attribute__((ext_vector_type(8))) short short8;   // 8 bf16 = 4 VGPRs (MFMA A/B frag)
typedef __attribute__((ext_vector_type(4))) float f32x4;    // MFMA C/D frag

// ---------------- bf16 split helpers ----------------
// a = hi + lo with hi = bf16_rne(a), lo = bf16_rne(a - hi). 3-term MFMA product
// hi*hi + lo*hi + hi*lo has relative error ~2^-18 (drops only lo*lo).
__device__ __forceinline__ void split8(const float4 a0, const float4 a1,
                                       short8& hi, short8& lo) {
    float a[8] = {a0.x, a0.y, a0.z, a0.w, a1.x, a1.y, a1.z, a1.w};
#pragma unroll
    for (int p = 0; p < 4; ++p) {
        float2 f = make_float2(a[2 * p], a[2 * p + 1]);
        __hip_bfloat162 h = __float22bfloat162_rn(f);          // v_cvt_pk_bf16_f32
        float2 hf = __bfloat1622float2(h);
        __hip_bfloat162 l = __float22bfloat162_rn(make_float2(f.x - hf.x, f.y - hf.y));
        union { __hip_bfloat162 b; short2 s; } uh, ul;
        uh.b = h; ul.b = l;
        hi[2 * p] = uh.s.x; hi[2 * p + 1] = uh.s.y;
        lo[2 * p] = ul.s.x; lo[2 * p + 1] = ul.s.y;
    }
}

// ---------------- weight prep: fp32 W -> bf16 hi/lo in B-fragment order ----------------
// Coalesced W reads (thread id = row-major (k,n) element); scattered writes.
// Chunk index is ITERATION order: cp = s*NT + ct (s-major), so the main kernel's
// prefetch ring walks ws linearly.
// Fragment layout for mfma_f32_16x16x32_bf16:
//   B: lane l holds B[k = s*32 + (l>>4)*8 + j][n = ct*16 + (l&15)]
// ws layout (shorts): chunk cp occupies 1024 shorts:
//   [cp*1024 + lane*8 + j] = hi, [cp*1024 + 512 + lane*8 + j] = lo.
// Layer bases (shorts): L0=0 (64x128), L1=16384 (128x128), L2=49152 (128x64), L3=65536 (64x32).
__global__ void prep_weights(const float* __restrict__ W0, const float* __restrict__ W1,
                             const float* __restrict__ W2, const float* __restrict__ W3,
                             short* __restrict__ ws) {
    int e = blockIdx.x * 256 + threadIdx.x;
    const float* W; int logN, base, el;
    if (e < 8192)       { W = W0; logN = 7; base = 0;     el = e; }
    else if (e < 24576) { W = W1; logN = 7; base = 16384; el = e - 8192; }
    else if (e < 32768) { W = W2; logN = 6; base = 49152; el = e - 24576; }
    else if (e < 34816) { W = W3; logN = 5; base = 65536; el = e - 32768; }
    else return;
    const int NT = 1 << (logN - 4);        // N/16
    int k = el >> logN;
    int n = el & ((1 << logN) - 1);
    int s = k >> 5, kl = k & 31;
    int lane = (kl >> 3) * 16 + (n & 15);
    int j = kl & 7;
    int ct = n >> 4;
    int cp = s * NT + ct;                  // s-major iteration order
    float w = W[el];                       // coalesced read
    __hip_bfloat16 h = __float2bfloat16(w);
    float hf = __bfloat162float(h);
    __hip_bfloat16 l = __float2bfloat16(w - hf);
    union { __hip_bfloat16 b; short s; } ph, pl;
    ph.b = h; pl.b = l;
    ws[base + cp * 1024 + lane * 8 + j] = ph.s;
    ws[base + cp * 1024 + 512 + lane * 8 + j] = pl.s;
}

// ---------------- per-wave layer compute with prefetch ring ----------------
template <int K, int N>
__device__ __forceinline__ void layer_frag(const short8* __restrict__ wf,
                                           const float* __restrict__ bias,
                                           const short8 ah[K / 32], const short8 al[K / 32],
                                           int lane, int m, f32x4* acc) {
    constexpr int NK = K / 32, NT = N / 16, CP = NK * NT;
    constexpr int W = (CP < 4) ? CP : 4;   // prefetch depth: 4 chunk-pairs = 32 VGPRs
    short8 rh[W], rl[W];
#pragma unroll
    for (int i = 0; i < W; ++i) {
        rh[i] = wf[(size_t)i * 128 + lane];
        rl[i] = wf[(size_t)i * 128 + 64 + lane];
    }
#pragma unroll
    for (int ct = 0; ct < NT; ++ct) {
        float b = bias[ct * 16 + m];
        acc[ct] = f32x4{b, b, b, b};
    }
#pragma unroll
    for (int i = 0; i < CP; ++i) {
        const int s = i / NT, ct = i % NT;   // s-major: consecutive i -> different acc[ct]
        short8 bh = rh[i % W], bl = rl[i % W];
        if (i + W < CP) {
            rh[i % W] = wf[(size_t)(i + W) * 128 + lane];
            rl[i % W] = wf[(size_t)(i + W) * 128 + 64 + lane];
        }
        acc[ct] = __builtin_amdgcn_mfma_f32_16x16x32_bf16(ah[s], bh, acc[ct], 0, 0, 0);
        acc[ct] = __builtin_amdgcn_mfma_f32_16x16x32_bf16(al[s], bh, acc[ct], 0, 0, 0);
        acc[ct] = __builtin_amdgcn_mfma_f32_16x16x32_bf16(ah[s], bl, acc[ct], 0, 0, 0);
    }
}

template <int K>
__device__ __forceinline__ void load_a_lds(const float* __restrict__ lw, int m, int q,
                                           short8 ah[K / 32], short8 al[K / 32]) {
    const float* rp = lw + m * PITCH + q * 8;
    float4 v[K / 16];
#pragma unroll
    for (int s = 0; s < K / 32; ++s) {       // all ds_read_b128 in flight first
        v[2 * s]     = *(const float4*)(rp + s * 32);
        v[2 * s + 1] = *(const float4*)(rp + s * 32 + 4);
    }
#pragma unroll
    for (int s = 0; s < K / 32; ++s) split8(v[2 * s], v[2 * s + 1], ah[s], al[s]);
}

template <int N>
__device__ __forceinline__ void store_d_lds(float* __restrict__ lw, int m, int q,
                                            const f32x4* acc, bool relu) {
#pragma unroll
    for (int ct = 0; ct < N / 16; ++ct) {
#pragma unroll
        for (int r = 0; r < 4; ++r) {
            float v = acc[ct][r];
            if (relu) v = fmaxf(v, 0.0f);
            lw[(q * 4 + r) * PITCH + ct * 16 + m] = v;
        }
    }
}

// ---------------- fast E1: Abramowitz-Stegun rational approximations ----------------
// li(1-u) = Ei(t) = -E1(-t), t = log(1-u) < 0; x = -t in (1e-4, 9.3).
// x < 1:  5.1.53 polynomial + log, |err| < 2e-7;  x >= 1: 5.1.54 rational, |err| < 2e-8.
__device__ __forceinline__ float expi_neg_fast(float t) {
    float x = -t;
    float e1s = -__logf(x) + (-0.57721566f + x * (0.99999193f + x * (-0.24991055f
              + x * (0.05519968f + x * (-0.00976004f + x * 0.00107857f)))));
    float num = 0.2677737343f + x * (8.6347608925f + x * (18.0590169730f
              + x * (8.5733287401f + x)));
    float den = 3.9584969228f + x * (21.0996530827f + x * (25.6329561486f
              + x * (9.5733223454f + x)));
    float e1l = __expf(-x) * num * __builtin_amdgcn_rcpf(x * den);
    float e1 = (x < 1.0f) ? e1s : e1l;
    return -e1;
}

__global__ __launch_bounds__(256, 4) void mlp_phi_mfma(
    const float* __restrict__ u,
    const float* __restrict__ b0, const float* __restrict__ b1,
    const float* __restrict__ b2, const float* __restrict__ b3,
    const short* __restrict__ ws,
    const float* __restrict__ var1, const float* __restrict__ var2,
    const float* __restrict__ var3, const float* __restrict__ var4,
    const float* __restrict__ var5, const float* __restrict__ var6,
    float* __restrict__ out) {
    // 4 waves/block, each wave owns 16 rows end-to-end. No __syncthreads anywhere.
    __shared__ float lds[4 * 16 * PITCH];   // 33792 B -> 4 blocks/CU
    const int t = threadIdx.x, lane = t & 63, wave = t >> 6;
    const int m = lane & 15, q = lane >> 4;
    float* lw = lds + wave * 16 * PITCH;
    const size_t row0 = (size_t)blockIdx.x * 64 + wave * 16;

    const short8* wf0 = (const short8*)(ws);
    const short8* wf1 = (const short8*)(ws + 16384);
    const short8* wf2 = (const short8*)(ws + 49152);
    const short8* wf3 = (const short8*)(ws + 65536);

    short8 ah[4], al[4];
    f32x4 acc[8];

    // ---- Layer 0 (64 -> 128): A straight from global u ----
    {
        const float* up = u + (row0 + m) * 64;
        float4 v[4];
#pragma unroll
        for (int s = 0; s < 2; ++s) {
            v[2 * s]     = *(const float4*)(up + s * 32 + q * 8);
            v[2 * s + 1] = *(const float4*)(up + s * 32 + q * 8 + 4);
        }
#pragma unroll
        for (int s = 0; s < 2; ++s) split8(v[2 * s], v[2 * s + 1], ah[s], al[s]);
    }
    layer_frag<64, 128>(wf0, b0, ah, al, lane, m, acc);
    store_d_lds<128>(lw, m, q, acc, true);

    // ---- Layer 1 (128 -> 128) ----
    load_a_lds<128>(lw, m, q, ah, al);
    layer_frag<128, 128>(wf1, b1, ah, al, lane, m, acc);
    store_d_lds<128>(lw, m, q, acc, true);

    // ---- Layer 2 (128 -> 64) ----
    load_a_lds<128>(lw, m, q, ah, al);
    layer_frag<128, 64>(wf2, b2, ah, al, lane, m, acc);
    store_d_lds<64>(lw, m, q, acc, true);

    // ---- Layer 3 (64 -> 32): net stays in registers ----
    load_a_lds<64>(lw, m, q, ah, al);

    // Prefetch epilogue u values so their latency hides behind layer-3 MFMAs.
    float ue[8];
#pragma unroll
    for (int ot = 0; ot < 2; ++ot)
#pragma unroll
        for (int r = 0; r < 4; ++r)
            ue[ot * 4 + r] = u[(row0 + q * 4 + r) * 64 + ot * 16 + m];

    layer_frag<64, 32>(wf3, b3, ah, al, lane, m, acc);   // acc[0..1] = net tiles

    // ---- Epilogue: lane holds net[row=q*4+r][col=ot*16+m] ----
#pragma unroll
    for (int ot = 0; ot < 2; ++ot) {
        const int d = ot * 16 + m;
        const float v1 = var1[d], v2 = var2[d], v3 = var3[d],
                    v4 = var4[d], v5 = var5[d], v6 = var6[d];
#pragma unroll
        for (int r = 0; r < 4; ++r) {
            const size_t row = row0 + q * 4 + r;
            const float net = acc[ot][r];
            const float ud = ue[ot * 4 + r];

            const float lt = __logf(1.0f - ud);      // log_term < 0
            const float li = expi_neg_fast(lt);
            const float omu = 1.0f - ud;

            const float rl = __builtin_amdgcn_rcpf(lt);   // 1/log_term
            const float phi = v2 * rl
                            + v3 * li
                            + v4 * (omu * rl - li)
                            + v5 * (omu * (lt + 1.0f) * 0.5f * (rl * rl) - 0.5f * li);

            const float ud2 = ud * ud;
            const float ud4 = ud2 * ud2;
            const float p01 = -4.0f * ud4 * ud + 5.0f * ud4;

            float corr1 = p01 * (v1 + phi);
            if (isnan(corr1)) {
                corr1 = 0.0f;
            } else if (isinf(corr1)) {
                corr1 = copysignf(FLT_MAX_F, corr1);
            }
            const float corr2 = v6 * (ud * ud2 - 2.0f * ud2 + ud);

            float nt = net + corr1 + corr2;
            nt = fmaxf(nt, 0.0f);

            const float base = (1.0f - ud2) * 0.5f;
            out[row * 32 + d] = __expf(-nt * __logf(base));
        }
    }
}

extern "C" void kernel_launch(void* const* d_in, const int* in_sizes, int n_in,
                              void* d_out, int out_size, void* d_ws, size_t ws_size,
                              hipStream_t stream) {
    const float* u    = (const float*)d_in[0];
    const float* W0   = (const float*)d_in[1];
    const float* b0   = (const float*)d_in[2];
    const float* W1   = (const float*)d_in[3];
    const float* b1   = (const float*)d_in[4];
    const float* W2   = (const float*)d_in[5];
    const float* b2   = (const float*)d_in[6];
    const float* W3   = (const float*)d_in[7];
    const float* b3   = (const float*)d_in[8];
    const float* var1 = (const float*)d_in[9];
    const float* var2 = (const float*)d_in[10];
    const float* var3 = (const float*)d_in[11];
    const float* var4 = (const float*)d_in[12];
    const float* var5 = (const float*)d_in[13];
    const float* var6 = (const float*)d_in[14];
    float* out = (float*)d_out;
    short* ws = (short*)d_ws;   // needs 139,264 B

    // Convert weights to bf16 hi/lo fragment layout (same work every launch).
    prep_weights<<<dim3(136), dim3(256), 0, stream>>>(W0, W1, W2, W3, ws);

    const int B = in_sizes[0] / 64;        // 262144 rows
    const int blocks = B / 64;             // 64 rows per block (16 per wave)
    mlp_phi_mfma<<<dim3(blocks), dim3(256), 0, stream>>>(
        u, b0, b1, b2, b3, ws,
        var1, var2, var3, var4, var5, var6, out);
}